// Round 1
// baseline (122401.001 us; speedup 1.0000x reference)
//
#include <hip/hip_runtime.h>
#include <math.h>

// EMD via entropic Sinkhorn, N=M=1024, D=3, eps=0.01 (inv_eps=100).
// Scaled log-domain: u=f/eps, v=g/eps, C'=100*C.
//   u_i = logN - LSE_j(v_j - C'_ij) ; v_j = logN - LSE_i(u_i - C'_ij)
// Persistent kernel, custom grid barrier (6000 barriers). Compute per
// half-iter is tiny; this is a synchronization-latency problem.

#define NPTS 1024
#define GB   256           // grid blocks (1 per CU; 1024 waves total -> co-resident)
#define TB   256           // threads per block (4 waves)
#define WPB  (TB / 64)     // waves per block = 4
#define RPB  (NPTS / GB)   // rows per block = 4 (one per wave)
#define KPL  (NPTS / 64)   // elements per lane per row = 16

__device__ __forceinline__ void grid_barrier(unsigned* cnt, unsigned phase) {
  __syncthreads();                       // drains this block's vmem writes too
  if (threadIdx.x == 0) {
    __threadfence();                     // release: flush XCD L2 (device scope)
    __hip_atomic_fetch_add(cnt, 1u, __ATOMIC_RELAXED, __HIP_MEMORY_SCOPE_AGENT);
    const unsigned target = phase * (unsigned)GB;
    while (__hip_atomic_load(cnt, __ATOMIC_RELAXED, __HIP_MEMORY_SCOPE_AGENT) < target) {
      __builtin_amdgcn_s_sleep(1);
    }
    __threadfence();                     // acquire: invalidate L1/L2 clean lines
  }
  __syncthreads();
}

// LSE over j of (w[j] - 100*||q - p_j||^2); all lanes return the full result.
__device__ __forceinline__ float row_lse(const float* __restrict__ px,
                                         const float* __restrict__ py,
                                         const float* __restrict__ pz,
                                         float qx, float qy, float qz,
                                         const float* __restrict__ w, int lane) {
  float s[KPL];
  float m = -__builtin_inff();
#pragma unroll
  for (int k = 0; k < KPL; ++k) {
    const int j = lane + 64 * k;         // conflict-free LDS pattern
    const float dx = qx - px[j], dy = qy - py[j], dz = qz - pz[j];
    const float c = fmaf(dx, dx, fmaf(dy, dy, dz * dz)) * 100.0f;
    s[k] = w[j] - c;
    m = fmaxf(m, s[k]);
  }
#pragma unroll
  for (int off = 32; off >= 1; off >>= 1) m = fmaxf(m, __shfl_xor(m, off));
  float sum = 0.0f;
#pragma unroll
  for (int k = 0; k < KPL; ++k) sum += expf(s[k] - m);
#pragma unroll
  for (int off = 32; off >= 1; off >>= 1) sum += __shfl_xor(sum, off);
  return m + logf(sum);
}

extern "C" __global__ void emd_init(float* wsf, float* out) {
  const int t = blockIdx.x * blockDim.x + threadIdx.x;
  if (t < 2 * NPTS) wsf[t] = 0.0f;                 // u, v = 0
  if (t == 2 * NPTS) ((unsigned*)wsf)[2 * NPTS] = 0u;  // barrier counter
  if (t == 0) out[0] = 0.0f;                       // output accumulator
}

extern "C" __global__ void __launch_bounds__(TB, 1)
emd_main(const float* __restrict__ tgt, const float* __restrict__ oup,
         const int* __restrict__ itp, float* __restrict__ wsf,
         float* __restrict__ out) {
  __shared__ float s_tx[NPTS], s_ty[NPTS], s_tz[NPTS];
  __shared__ float s_ox[NPTS], s_oy[NPTS], s_oz[NPTS];
  __shared__ float s_w[NPTS];
  __shared__ float s_acc[WPB];

  float* g_u = wsf;
  float* g_v = wsf + NPTS;
  unsigned* cnt = (unsigned*)(wsf + 2 * NPTS);     // byte offset 8192, own line

  const int tid  = threadIdx.x;
  const int lane = tid & 63;
  const int wave = tid >> 6;
  const int row  = blockIdx.x * RPB + wave;        // this wave's row AND column

  for (int i = tid; i < NPTS; i += TB) {
    s_tx[i] = tgt[3 * i + 0]; s_ty[i] = tgt[3 * i + 1]; s_tz[i] = tgt[3 * i + 2];
    s_ox[i] = oup[3 * i + 0]; s_oy[i] = oup[3 * i + 1]; s_oz[i] = oup[3 * i + 2];
  }
  const int niter = *itp;
  const float LOGN = -logf((float)NPTS);           // log_a == log_b
  __syncthreads();

  const float tx = s_tx[row], ty = s_ty[row], tz = s_tz[row];
  const float ox = s_ox[row], oy = s_oy[row], oz = s_oz[row];

  unsigned phase = 0;
  for (int it = 0; it < niter; ++it) {
    // ---- f-pass: u[row] = LOGN - LSE_j(v[j] - C'[row][j])
    ((float4*)s_w)[tid] = ((const float4*)g_v)[tid];
    __syncthreads();
    {
      const float lse = row_lse(s_ox, s_oy, s_oz, tx, ty, tz, s_w, lane);
      if (lane == 0) g_u[row] = LOGN - lse;
    }
    grid_barrier(cnt, ++phase);

    // ---- g-pass: v[col] = LOGN - LSE_i(u[i] - C'[i][col])   (col == row)
    ((float4*)s_w)[tid] = ((const float4*)g_u)[tid];
    __syncthreads();
    {
      const float lse = row_lse(s_tx, s_ty, s_tz, ox, oy, oz, s_w, lane);
      if (lane == 0) g_v[row] = LOGN - lse;
    }
    grid_barrier(cnt, ++phase);
  }

  // ---- objective: sum_ij exp(u_i + v_j - C'_ij) * C_ij,  C = C'/100
  ((float4*)s_w)[tid] = ((const float4*)g_v)[tid];
  __syncthreads();
  const float u_r = g_u[row];
  float acc = 0.0f;
#pragma unroll
  for (int k = 0; k < KPL; ++k) {
    const int j = lane + 64 * k;
    const float dx = tx - s_ox[j], dy = ty - s_oy[j], dz = tz - s_oz[j];
    const float c = fmaf(dx, dx, fmaf(dy, dy, dz * dz)) * 100.0f;
    const float p = expf(u_r + s_w[j] - c);
    acc = fmaf(p, c, acc);
  }
#pragma unroll
  for (int off = 32; off >= 1; off >>= 1) acc += __shfl_xor(acc, off);
  if (lane == 0) s_acc[wave] = acc;
  __syncthreads();
  if (tid == 0) {
    float t = 0.0f;
    for (int w = 0; w < WPB; ++w) t += s_acc[w];
    atomicAdd(out, t * 0.01f);
  }
}

extern "C" void kernel_launch(void* const* d_in, const int* in_sizes, int n_in,
                              void* d_out, int out_size, void* d_ws, size_t ws_size,
                              hipStream_t stream) {
  const float* tgt = (const float*)d_in[0];
  const float* oup = (const float*)d_in[1];
  const int*   itp = (const int*)d_in[2];
  float* wsf = (float*)d_ws;
  float* out = (float*)d_out;

  hipLaunchKernelGGL(emd_init, dim3(9), dim3(256), 0, stream, wsf, out);
  hipLaunchKernelGGL(emd_main, dim3(GB), dim3(TB), 0, stream,
                     tgt, oup, itp, wsf, out);
}

// Round 2
// 2957.520 us; speedup vs baseline: 41.3864x; 41.3864x over previous
//
#include <hip/hip_runtime.h>
#include <math.h>

// EMD via entropic Sinkhorn, N=M=1024, D=3, eps=0.01 (inv_eps=100).
// Scaled log-domain: u=f/eps, v=g/eps, C'=100*C.
// Persistent kernel, fence-free grid barrier: ALL cross-block data moves via
// agent-scope relaxed atomics (cache-bypassing, coherent at the fabric point),
// so no buffer_wbl2/buffer_inv L2 flushes are needed (round-1 cost: 20us/barrier).
// Exact early exit: detect bitwise period-2 fixed point of v locally per block.

#define NPTS 1024
#define GB   64            // blocks (1024 waves total; trivially co-resident)
#define TB   1024          // threads per block = 16 waves, 1 row per wave
#define WPB  (TB / 64)     // 16
#define RPB  (NPTS / GB)   // 16 rows per block
#define KPL  (NPTS / 64)   // 16 elements per lane per row

__device__ __forceinline__ float agload(const float* p) {
  return __hip_atomic_load(p, __ATOMIC_RELAXED, __HIP_MEMORY_SCOPE_AGENT);
}
__device__ __forceinline__ void agstore(float* p, float v) {
  __hip_atomic_store(p, v, __ATOMIC_RELAXED, __HIP_MEMORY_SCOPE_AGENT);
}

__device__ __forceinline__ void grid_barrier(unsigned* cnt, unsigned phase) {
  __syncthreads();                 // drains all threads' vmcnt (sc1 stores visible)
  if (threadIdx.x == 0) {
    __hip_atomic_fetch_add(cnt, 1u, __ATOMIC_RELAXED, __HIP_MEMORY_SCOPE_AGENT);
    const unsigned target = phase * (unsigned)GB;
    while (__hip_atomic_load(cnt, __ATOMIC_RELAXED, __HIP_MEMORY_SCOPE_AGENT) < target) {
      __builtin_amdgcn_s_sleep(1);
    }
  }
  __syncthreads();
}

// LSE over j of (w[j] - 100*||q - p_j||^2); all lanes return the full result.
// Arithmetic identical to round 1 (which matched the reference bitwise).
__device__ __forceinline__ float row_lse(const float* __restrict__ px,
                                         const float* __restrict__ py,
                                         const float* __restrict__ pz,
                                         float qx, float qy, float qz,
                                         const float* __restrict__ w, int lane) {
  float s[KPL];
  float m = -__builtin_inff();
#pragma unroll
  for (int k = 0; k < KPL; ++k) {
    const int j = lane + 64 * k;
    const float dx = qx - px[j], dy = qy - py[j], dz = qz - pz[j];
    const float c = fmaf(dx, dx, fmaf(dy, dy, dz * dz)) * 100.0f;
    s[k] = w[j] - c;
    m = fmaxf(m, s[k]);
  }
#pragma unroll
  for (int off = 32; off >= 1; off >>= 1) m = fmaxf(m, __shfl_xor(m, off));
  float sum = 0.0f;
#pragma unroll
  for (int k = 0; k < KPL; ++k) sum += expf(s[k] - m);
#pragma unroll
  for (int off = 32; off >= 1; off >>= 1) sum += __shfl_xor(sum, off);
  return m + logf(sum);
}

extern "C" __global__ void emd_init(float* wsf, float* out) {
  const int t = blockIdx.x * blockDim.x + threadIdx.x;
  if (t < 2 * NPTS) wsf[t] = 0.0f;                     // u, v = 0
  if (t == 2 * NPTS) ((unsigned*)wsf)[2 * NPTS] = 0u;  // barrier counter
  if (t == 0) out[0] = 0.0f;                           // output accumulator
}

extern "C" __global__ void __launch_bounds__(TB, 1)
emd_main(const float* __restrict__ tgt, const float* __restrict__ oup,
         const int* __restrict__ itp, float* __restrict__ wsf,
         float* __restrict__ out) {
  __shared__ float s_tx[NPTS], s_ty[NPTS], s_tz[NPTS];
  __shared__ float s_ox[NPTS], s_oy[NPTS], s_oz[NPTS];
  __shared__ float s_w[NPTS];
  __shared__ float s_acc[WPB];

  float* g_u = wsf;
  float* g_v = wsf + NPTS;
  unsigned* cnt = (unsigned*)(wsf + 2 * NPTS);

  const int tid  = threadIdx.x;
  const int lane = tid & 63;
  const int wave = tid >> 6;
  const int row  = blockIdx.x * RPB + wave;   // this wave's row AND column

  // stage points (TB == NPTS: one point per thread)
  s_tx[tid] = tgt[3 * tid + 0]; s_ty[tid] = tgt[3 * tid + 1]; s_tz[tid] = tgt[3 * tid + 2];
  s_ox[tid] = oup[3 * tid + 0]; s_oy[tid] = oup[3 * tid + 1]; s_oz[tid] = oup[3 * tid + 2];
  const int niter = *itp;
  const float LOGN = -logf((float)NPTS);
  __syncthreads();

  const float tx = s_tx[row], ty = s_ty[row], tz = s_tz[row];
  const float ox = s_ox[row], oy = s_oy[row], oz = s_oz[row];

  float v_prev  = __builtin_nanf("");   // NaN: compares unequal -> no false exit
  float v_prev2 = __builtin_nanf("");
  unsigned phase = 0;

  for (int it = 0; it < niter; ++it) {
    // ---- load v_t; bitwise period-2 convergence check (exact, local to block)
    const float vj = agload(g_v + tid);
    const int same2 = (vj == v_prev2);
    v_prev2 = v_prev; v_prev = vj;
    s_w[tid] = vj;
    const int conv = __syncthreads_and(same2);  // also the barrier for s_w
    // period-2 cycle: remaining iterations are identity iff remaining is even
    if (conv && (((niter - it) & 1) == 0)) break;

    // ---- f-pass: u[row] = LOGN - LSE_j(v[j] - C'[row][j])
    float lse = row_lse(s_ox, s_oy, s_oz, tx, ty, tz, s_w, lane);
    if (lane == 0) agstore(g_u + row, LOGN - lse);
    grid_barrier(cnt, ++phase);

    // ---- g-pass: v[col] = LOGN - LSE_i(u[i] - C'[i][col])   (col == row)
    s_w[tid] = agload(g_u + tid);
    __syncthreads();
    lse = row_lse(s_tx, s_ty, s_tz, ox, oy, oz, s_w, lane);
    if (lane == 0) agstore(g_v + row, LOGN - lse);
    grid_barrier(cnt, ++phase);
  }

  // ---- objective: sum_ij exp(u_i + v_j - C'_ij) * C'_ij / 100
  s_w[tid] = agload(g_v + tid);
  __syncthreads();
  float u_r = (lane == 0) ? agload(g_u + row) : 0.0f;
  u_r = __shfl(u_r, 0);
  float acc = 0.0f;
#pragma unroll
  for (int k = 0; k < KPL; ++k) {
    const int j = lane + 64 * k;
    const float dx = tx - s_ox[j], dy = ty - s_oy[j], dz = tz - s_oz[j];
    const float c = fmaf(dx, dx, fmaf(dy, dy, dz * dz)) * 100.0f;
    acc = fmaf(expf(u_r + s_w[j] - c), c, acc);
  }
#pragma unroll
  for (int off = 32; off >= 1; off >>= 1) acc += __shfl_xor(acc, off);
  if (lane == 0) s_acc[wave] = acc;
  __syncthreads();
  if (tid == 0) {
    float t = 0.0f;
    for (int w = 0; w < WPB; ++w) t += s_acc[w];
    atomicAdd(out, t * 0.01f);
  }
}

extern "C" void kernel_launch(void* const* d_in, const int* in_sizes, int n_in,
                              void* d_out, int out_size, void* d_ws, size_t ws_size,
                              hipStream_t stream) {
  const float* tgt = (const float*)d_in[0];
  const float* oup = (const float*)d_in[1];
  const int*   itp = (const int*)d_in[2];
  float* wsf = (float*)d_ws;
  float* out = (float*)d_out;

  hipLaunchKernelGGL(emd_init, dim3(9), dim3(256), 0, stream, wsf, out);
  hipLaunchKernelGGL(emd_main, dim3(GB), dim3(TB), 0, stream,
                     tgt, oup, itp, wsf, out);
}

// Round 3
// 2175.753 us; speedup vs baseline: 56.2568x; 1.3593x over previous
//
#include <hip/hip_runtime.h>
#include <math.h>

// EMD via entropic Sinkhorn, N=M=1024, D=3, eps=0.01.
// Scaled log domain: u=f*100, v=g*100, c'=100*||t_i-o_j||^2.
//   u_i = LOGN - (m + log SUM_j e^{v_j-m} * e^{-c'_ij})   (m = max_j v_j)
//   v_j = LOGN - (m + log SUM_i e^{u_i-m} * e^{-c'_ij})
// e^{-c'} is iteration-invariant -> lives in REGISTERS (64 VGPR/thread).
// Cross-block sync: tagged 8-byte slots {iter_tag|payload}; consumers poll
// for the exact tag. Every block polls ALL 1024 slots and syncs before its
// stores, so a tag t+1 store proves all blocks finished reading tag t.

#define NPTS 1024
#define GB   64
#define TB   512
#define WPB  (TB / 64)       // 8 waves
#define RPB  (NPTS / GB)     // 16 rows (and cols) per block
#define RPW  (RPB / WPB)     // 2 rows per wave
#define DELTA 1e-6f          // early-exit tolerance in v-domain (1-2 ulps)

typedef unsigned long long ull;

static __device__ __forceinline__ ull sload(const ull* p) {
  return __hip_atomic_load(p, __ATOMIC_RELAXED, __HIP_MEMORY_SCOPE_AGENT);
}
static __device__ __forceinline__ void sstore(ull* p, ull x) {
  __hip_atomic_store(p, x, __ATOMIC_RELAXED, __HIP_MEMORY_SCOPE_AGENT);
}
static __device__ __forceinline__ ull pack(unsigned tag, float v) {
  return ((ull)tag << 32) | (ull)__float_as_uint(v);
}

extern "C" __global__ void emd_init(ull* ws, float* out) {
  const int t = blockIdx.x * blockDim.x + threadIdx.x;
  if (t < 2 * NPTS) ws[t] = 0ull;        // u,v slots: tag 0, payload 0.0f
  if (t == 0) out[0] = 0.0f;
}

extern "C" __global__ void __launch_bounds__(TB, 1)
emd_main(const float* __restrict__ tgt, const float* __restrict__ oup,
         const int* __restrict__ itp, ull* __restrict__ ws,
         float* __restrict__ out) {
  ull* us = ws;              // u slots [NPTS]
  ull* vs = ws + NPTS;       // v slots [NPTS]

  __shared__ float s_tx[NPTS], s_ty[NPTS], s_tz[NPTS];
  __shared__ float s_ox[NPTS], s_oy[NPTS], s_oz[NPTS];
  __shared__ __align__(16) float s_E[NPTS];
  __shared__ float s_U[NPTS];
  __shared__ float s_wm[2][WPB];
  __shared__ float s_rs[WPB];

  const int tid = threadIdx.x, lane = tid & 63, wave = tid >> 6;
  const int r0 = blockIdx.x * RPB;
  const int s0i = tid, s1i = tid + TB;   // this thread's two slot indices

  for (int i = tid; i < NPTS; i += TB) {
    s_tx[i] = tgt[3*i+0]; s_ty[i] = tgt[3*i+1]; s_tz[i] = tgt[3*i+2];
    s_ox[i] = oup[3*i+0]; s_oy[i] = oup[3*i+1]; s_oz[i] = oup[3*i+2];
  }
  const int niter = *itp;
  const float LOGN = -logf((float)NPTS);
  __syncthreads();

  // ---- register-resident e^{-c'} tables (iteration-invariant) ----
  float pcf[RPW][16], pcg[RPW][16];
#pragma unroll
  for (int rr = 0; rr < RPW; ++rr) {
    const int row = r0 + RPW * wave + rr;   // wave's row (f) == wave's col (g)
    const float tx = s_tx[row], ty = s_ty[row], tz = s_tz[row];
    const float ox = s_ox[row], oy = s_oy[row], oz = s_oz[row];
#pragma unroll
    for (int kk = 0; kk < 4; ++kk)
#pragma unroll
      for (int c = 0; c < 4; ++c) {
        const int j = 256 * kk + 4 * lane + c;
        float dx = tx - s_ox[j], dy = ty - s_oy[j], dz = tz - s_oz[j];
        const float cf = fmaf(dx, dx, fmaf(dy, dy, dz * dz)) * 100.0f;
        dx = s_tx[j] - ox; dy = s_ty[j] - oy; dz = s_tz[j] - oz;
        const float cg = fmaf(dx, dx, fmaf(dy, dy, dz * dz)) * 100.0f;
        pcf[rr][4 * kk + c] = expf(-cf);
        pcg[rr][4 * kk + c] = expf(-cg);
      }
  }

  float h1a = __builtin_nanf(""), h1b = __builtin_nanf("");
  float h2a = __builtin_nanf(""), h2b = __builtin_nanf("");
  int it_stop = niter;

  for (int it = 0; it < niter; ++it) {
    // ===== f-pass: consume v(tag=it), produce u(tag=it+1) =====
    ull x0, x1;
    for (;;) {
      x0 = sload(vs + s0i); x1 = sload(vs + s1i);
      if ((unsigned)(x0 >> 32) == (unsigned)it &&
          (unsigned)(x1 >> 32) == (unsigned)it) break;
    }
    const float v0 = __uint_as_float((unsigned)x0);
    const float v1 = __uint_as_float((unsigned)x1);
    const bool cv = (fabsf(v0 - h2a) <= DELTA) & (fabsf(v1 - h2b) <= DELTA);
    h2a = h1a; h2b = h1b; h1a = v0; h1b = v1;

    float wm = fmaxf(v0, v1);
#pragma unroll
    for (int off = 32; off >= 1; off >>= 1) wm = fmaxf(wm, __shfl_xor(wm, off));
    if (lane == 0) s_wm[0][wave] = wm;
    const int conv = __syncthreads_and((int)cv);
    if (conv) { it_stop = it; break; }     // uniform across blocks (same bits)
    float m = s_wm[0][0];
#pragma unroll
    for (int w = 1; w < WPB; ++w) m = fmaxf(m, s_wm[0][w]);
    s_E[s0i] = expf(v0 - m);
    s_E[s1i] = expf(v1 - m);
    __syncthreads();

    {
      const float4* E4 = (const float4*)s_E;
      float sum[RPW];
#pragma unroll
      for (int rr = 0; rr < RPW; ++rr) {
        float a0 = 0.f, a1 = 0.f, a2 = 0.f, a3 = 0.f;
#pragma unroll
        for (int kk = 0; kk < 4; ++kk) {
          const float4 e = E4[64 * kk + lane];
          a0 = fmaf(pcf[rr][4 * kk + 0], e.x, a0);
          a1 = fmaf(pcf[rr][4 * kk + 1], e.y, a1);
          a2 = fmaf(pcf[rr][4 * kk + 2], e.z, a2);
          a3 = fmaf(pcf[rr][4 * kk + 3], e.w, a3);
        }
        float a = (a0 + a1) + (a2 + a3);
#pragma unroll
        for (int off = 32; off >= 1; off >>= 1) a += __shfl_xor(a, off);
        sum[rr] = a;
      }
      if (lane == 0) {
#pragma unroll
        for (int rr = 0; rr < RPW; ++rr)
          sstore(us + (r0 + RPW * wave + rr),
                 pack((unsigned)(it + 1), LOGN - (m + logf(sum[rr]))));
      }
    }

    // ===== g-pass: consume u(tag=it+1), produce v(tag=it+1) =====
    for (;;) {
      x0 = sload(us + s0i); x1 = sload(us + s1i);
      if ((unsigned)(x0 >> 32) == (unsigned)(it + 1) &&
          (unsigned)(x1 >> 32) == (unsigned)(it + 1)) break;
    }
    const float u0 = __uint_as_float((unsigned)x0);
    const float u1 = __uint_as_float((unsigned)x1);
    wm = fmaxf(u0, u1);
#pragma unroll
    for (int off = 32; off >= 1; off >>= 1) wm = fmaxf(wm, __shfl_xor(wm, off));
    if (lane == 0) s_wm[1][wave] = wm;
    __syncthreads();
    float mg = s_wm[1][0];
#pragma unroll
    for (int w = 1; w < WPB; ++w) mg = fmaxf(mg, s_wm[1][w]);
    s_E[s0i] = expf(u0 - mg);
    s_E[s1i] = expf(u1 - mg);
    __syncthreads();

    {
      const float4* E4 = (const float4*)s_E;
      float sum[RPW];
#pragma unroll
      for (int rr = 0; rr < RPW; ++rr) {
        float a0 = 0.f, a1 = 0.f, a2 = 0.f, a3 = 0.f;
#pragma unroll
        for (int kk = 0; kk < 4; ++kk) {
          const float4 e = E4[64 * kk + lane];
          a0 = fmaf(pcg[rr][4 * kk + 0], e.x, a0);
          a1 = fmaf(pcg[rr][4 * kk + 1], e.y, a1);
          a2 = fmaf(pcg[rr][4 * kk + 2], e.z, a2);
          a3 = fmaf(pcg[rr][4 * kk + 3], e.w, a3);
        }
        float a = (a0 + a1) + (a2 + a3);
#pragma unroll
        for (int off = 32; off >= 1; off >>= 1) a += __shfl_xor(a, off);
        sum[rr] = a;
      }
      if (lane == 0) {
#pragma unroll
        for (int rr = 0; rr < RPW; ++rr)
          sstore(vs + (r0 + RPW * wave + rr),
                 pack((unsigned)(it + 1), LOGN - (mg + logf(sum[rr]))));
      }
    }
  }

  // ===== objective: sum_ij exp(u_i+v_j-c') * c' / 100  at tag it_stop =====
  {
    ull x0, x1, y0, y1;
    for (;;) {
      x0 = sload(vs + s0i); x1 = sload(vs + s1i);
      y0 = sload(us + s0i); y1 = sload(us + s1i);
      if ((unsigned)(x0 >> 32) == (unsigned)it_stop &&
          (unsigned)(x1 >> 32) == (unsigned)it_stop &&
          (unsigned)(y0 >> 32) == (unsigned)it_stop &&
          (unsigned)(y1 >> 32) == (unsigned)it_stop) break;
    }
    s_E[s0i] = __uint_as_float((unsigned)x0);   // v
    s_E[s1i] = __uint_as_float((unsigned)x1);
    s_U[s0i] = __uint_as_float((unsigned)y0);   // u
    s_U[s1i] = __uint_as_float((unsigned)y1);
    __syncthreads();

    float wsum = 0.f;
#pragma unroll
    for (int rr = 0; rr < RPW; ++rr) {
      const int row = r0 + RPW * wave + rr;
      const float u_r = s_U[row];
      const float tx = s_tx[row], ty = s_ty[row], tz = s_tz[row];
      float a = 0.f;
#pragma unroll
      for (int kk = 0; kk < 4; ++kk)
#pragma unroll
        for (int c = 0; c < 4; ++c) {
          const int j = 256 * kk + 4 * lane + c;
          const float dx = tx - s_ox[j], dy = ty - s_oy[j], dz = tz - s_oz[j];
          const float cc = fmaf(dx, dx, fmaf(dy, dy, dz * dz)) * 100.0f;
          a = fmaf(expf(u_r + s_E[j] - cc), cc, a);
        }
#pragma unroll
      for (int off = 32; off >= 1; off >>= 1) a += __shfl_xor(a, off);
      wsum += a;
    }
    if (lane == 0) s_rs[wave] = wsum;
    __syncthreads();
    if (tid == 0) {
      float t = 0.f;
#pragma unroll
      for (int w = 0; w < WPB; ++w) t += s_rs[w];
      atomicAdd(out, t * 0.01f);
    }
  }
}

extern "C" void kernel_launch(void* const* d_in, const int* in_sizes, int n_in,
                              void* d_out, int out_size, void* d_ws, size_t ws_size,
                              hipStream_t stream) {
  const float* tgt = (const float*)d_in[0];
  const float* oup = (const float*)d_in[1];
  const int*   itp = (const int*)d_in[2];
  ull* ws = (ull*)d_ws;
  float* out = (float*)d_out;

  hipLaunchKernelGGL(emd_init, dim3(8), dim3(256), 0, stream, ws, out);
  hipLaunchKernelGGL(emd_main, dim3(GB), dim3(TB), 0, stream,
                     tgt, oup, itp, ws, out);
}